// Round 1
// baseline (86.466 us; speedup 1.0000x reference)
//
#include <hip/hip_runtime.h>

// Problem dims (compile-time constants from the reference)
#define BB 512
#define HH 32
#define LL 7
#define SS 5
#define OO 8
#define NN (BB * HH)          // 16384 independent cells
#define DIST_THRESHOLD 0.1f

__global__ __launch_bounds__(64)
void PrimitiveCollisionCost_19533511262442_kernel(
    const float* __restrict__ pos,    // [N,L,3]
    const float* __restrict__ rot,    // [N,L,3,3]
    const float* __restrict__ off,    // [L,S,3]
    const float* __restrict__ srad,   // [L,S]
    const float* __restrict__ oc,     // [O,3]
    const float* __restrict__ orad,   // [O]
    const float* __restrict__ weight, // [1]
    float* __restrict__ out)          // [N]
{
    const int n = blockIdx.x * blockDim.x + threadIdx.x;
    if (n >= NN) return;

    const float w = weight[0];
    const float* posn = pos + (size_t)n * (LL * 3);
    const float* rotn = rot + (size_t)n * (LL * 9);

    float cost = 0.0f;

    // Keep l rolled (bounds code size); s/o fully unrolled for ILP.
    for (int l = 0; l < LL; ++l) {
        const float px = posn[l * 3 + 0];
        const float py = posn[l * 3 + 1];
        const float pz = posn[l * 3 + 2];

        const float r00 = rotn[l * 9 + 0];
        const float r01 = rotn[l * 9 + 1];
        const float r02 = rotn[l * 9 + 2];
        const float r10 = rotn[l * 9 + 3];
        const float r11 = rotn[l * 9 + 4];
        const float r12 = rotn[l * 9 + 5];
        const float r20 = rotn[l * 9 + 6];
        const float r21 = rotn[l * 9 + 7];
        const float r22 = rotn[l * 9 + 8];

        float best = -1e30f;

#pragma unroll
        for (int s = 0; s < SS; ++s) {
            // sphere_offsets / sphere_radii: loop-uniform indices -> scalar loads
            const float ox = off[(l * SS + s) * 3 + 0];
            const float oy = off[(l * SS + s) * 3 + 1];
            const float oz = off[(l * SS + s) * 3 + 2];
            const float rs = srad[l * SS + s];

            // world-frame sphere center: c = R @ o + p
            const float cx = r00 * ox + r01 * oy + r02 * oz + px;
            const float cy = r10 * ox + r11 * oy + r12 * oz + py;
            const float cz = r20 * ox + r21 * oy + r22 * oz + pz;

#pragma unroll
            for (int o = 0; o < OO; ++o) {
                const float dx = cx - oc[o * 3 + 0];
                const float dy = cy - oc[o * 3 + 1];
                const float dz = cz - oc[o * 3 + 2];
                const float d  = sqrtf(dx * dx + dy * dy + dz * dz);
                const float sg = rs + orad[o] - d;   // positive = penetration
                best = fmaxf(best, sg);
            }
        }

        // clamp-scale chain: clip(best + 0.1, 0, 0.2) / 0.25
        const float dist = fminf(fmaxf(best + DIST_THRESHOLD, 0.0f), 0.2f) * 4.0f;
        cost += dist;
    }

    out[n] = w * cost;
}

extern "C" void kernel_launch(void* const* d_in, const int* in_sizes, int n_in,
                              void* d_out, int out_size, void* d_ws, size_t ws_size,
                              hipStream_t stream) {
    const float* pos    = (const float*)d_in[0];  // link_pos_seq  [B,H,L,3]
    const float* rot    = (const float*)d_in[1];  // link_rot_seq  [B,H,L,3,3]
    const float* off    = (const float*)d_in[2];  // sphere_offsets [L,S,3]
    const float* srad   = (const float*)d_in[3];  // sphere_radii  [L,S]
    const float* oc     = (const float*)d_in[4];  // obj_centers   [O,3]
    const float* orad   = (const float*)d_in[5];  // obj_radii     [O]
    const float* weight = (const float*)d_in[6];  // scalar
    float* out = (float*)d_out;                   // [B,H] = [N]

    constexpr int block = 64;
    constexpr int grid  = (NN + block - 1) / block;  // 256 blocks -> 1/CU

    PrimitiveCollisionCost_19533511262442_kernel<<<grid, block, 0, stream>>>(
        pos, rot, off, srad, oc, orad, weight, out);
}

// Round 2
// 72.399 us; speedup vs baseline: 1.1943x; 1.1943x over previous
//
#include <hip/hip_runtime.h>

// Problem dims (compile-time constants from the reference)
#define BB 512
#define HH 32
#define LL 7
#define SS 5
#define OO 8
#define NN (BB * HH)          // 16384 independent cells
#define DIST_THRESHOLD 0.1f

// One thread per (n, l) pair, 8 lanes per n (lane l==7 idle -> contributes 0).
// 131072 threads = 512 blocks x 256 = 8 waves/CU (vs 1 wave/CU in R1).
__global__ __launch_bounds__(256)
void PrimitiveCollisionCost_19533511262442_kernel(
    const float* __restrict__ pos,    // [N,L,3]
    const float* __restrict__ rot,    // [N,L,3,3]
    const float* __restrict__ off,    // [L,S,3]
    const float* __restrict__ srad,   // [L,S]
    const float* __restrict__ oc,     // [O,3]
    const float* __restrict__ orad,   // [O]
    const float* __restrict__ weight, // [1]
    float* __restrict__ out)          // [N]
{
    const int t = blockIdx.x * blockDim.x + threadIdx.x;
    const int n = t >> 3;        // cell index
    const int l = t & 7;         // link index (7 == idle lane)

    float dist = 0.0f;

    if (l < LL) {
        const float* posn = pos + (size_t)n * (LL * 3) + l * 3;
        const float* rotn = rot + (size_t)n * (LL * 9) + l * 9;

        const float px = posn[0];
        const float py = posn[1];
        const float pz = posn[2];

        const float r00 = rotn[0];
        const float r01 = rotn[1];
        const float r02 = rotn[2];
        const float r10 = rotn[3];
        const float r11 = rotn[4];
        const float r12 = rotn[5];
        const float r20 = rotn[6];
        const float r21 = rotn[7];
        const float r22 = rotn[8];

        float best = -1e30f;

#pragma unroll
        for (int s = 0; s < SS; ++s) {
            const float ox = off[(l * SS + s) * 3 + 0];
            const float oy = off[(l * SS + s) * 3 + 1];
            const float oz = off[(l * SS + s) * 3 + 2];
            const float rs = srad[l * SS + s];

            // world-frame sphere center: c = R @ o + p
            const float cx = r00 * ox + r01 * oy + r02 * oz + px;
            const float cy = r10 * ox + r11 * oy + r12 * oz + py;
            const float cz = r20 * ox + r21 * oy + r22 * oz + pz;

#pragma unroll
            for (int o = 0; o < OO; ++o) {
                const float dx = cx - oc[o * 3 + 0];
                const float dy = cy - oc[o * 3 + 1];
                const float dz = cz - oc[o * 3 + 2];
                const float d  = sqrtf(dx * dx + dy * dy + dz * dz);
                const float sg = rs + orad[o] - d;   // positive = penetration
                best = fmaxf(best, sg);
            }
        }

        // clip(best + 0.1, 0, 0.2) / 0.25
        dist = fminf(fmaxf(best + DIST_THRESHOLD, 0.0f), 0.2f) * 4.0f;
    }

    // Sum the 7 link costs across the 8-lane group (xor butterfly stays
    // within the group for masks < 8).
    dist += __shfl_xor(dist, 1, 64);
    dist += __shfl_xor(dist, 2, 64);
    dist += __shfl_xor(dist, 4, 64);

    if (l == 0) {
        out[n] = weight[0] * dist;
    }
}

extern "C" void kernel_launch(void* const* d_in, const int* in_sizes, int n_in,
                              void* d_out, int out_size, void* d_ws, size_t ws_size,
                              hipStream_t stream) {
    const float* pos    = (const float*)d_in[0];  // link_pos_seq  [B,H,L,3]
    const float* rot    = (const float*)d_in[1];  // link_rot_seq  [B,H,L,3,3]
    const float* off    = (const float*)d_in[2];  // sphere_offsets [L,S,3]
    const float* srad   = (const float*)d_in[3];  // sphere_radii  [L,S]
    const float* oc     = (const float*)d_in[4];  // obj_centers   [O,3]
    const float* orad   = (const float*)d_in[5];  // obj_radii     [O]
    const float* weight = (const float*)d_in[6];  // scalar
    float* out = (float*)d_out;                   // [B,H] = [N]

    constexpr int block = 256;
    constexpr int grid  = (NN * 8) / block;  // 512 blocks, 8 waves/CU

    PrimitiveCollisionCost_19533511262442_kernel<<<grid, block, 0, stream>>>(
        pos, rot, off, srad, oc, orad, weight, out);
}